// Round 7
// baseline (1388.192 us; speedup 1.0000x reference)
//
#include <hip/hip_runtime.h>
#include <math.h>

// MetaNETS Langevin sampler, MI355X — round 7: one wave per batch element.
// R6 falsified LDS-residency theory (LDS halved, dur unchanged): the wall is
// ceil(8/R) rounds of a barrier-dominated per-block critical path (140
// __syncthreads). Fix: 64-thread blocks, wave loops over its own 4 m-tiles ->
// zero block barriers (intra-wave lgkm drains only), 4x per-wave ILP, and at
// ~17.8KB LDS all 8 blocks/CU are resident at once (single round, no tail).
// tau aliases h1f per m-tile (af in regs before scatter; disjoint unit sets).

#define B_TOT 2048
#define NPT   64
#define ZD    64
#define HD    128

typedef short bh8 __attribute__((ext_vector_type(8)));   // 8 x bf16 (4 VGPR)
typedef float fx4 __attribute__((ext_vector_type(4)));   // MFMA C/D

__device__ __forceinline__ float sigf(float x) {
  return __builtin_amdgcn_rcpf(1.0f + __expf(-x));
}
__device__ __forceinline__ unsigned int bfb(float x) {   // fp32 -> bf16 bits (RNE)
  unsigned int u = __float_as_uint(x);
  u += 0x7FFFu + ((u >> 16) & 1u);
  return u >> 16;
}
__device__ __forceinline__ unsigned int packbf(float a, float b) {
  unsigned int ua = __float_as_uint(a), ub = __float_as_uint(b);
  ua += 0x7FFFu + ((ua >> 16) & 1u);
  ub += 0x7FFFu + ((ub >> 16) & 1u);
  return (ua >> 16) | (ub & 0xFFFF0000u);
}
__device__ __forceinline__ float wsum64(float v) {
  #pragma unroll
  for (int d = 1; d < 64; d <<= 1) v += __shfl_xor(v, d, 64);
  return v;
}
__device__ __forceinline__ void wave_sync() {   // intra-wave LDS order + drain
  __builtin_amdgcn_wave_barrier();
  __builtin_amdgcn_s_waitcnt(0xC07F);           // lgkmcnt(0)
  __builtin_amdgcn_wave_barrier();
}

// B-frag arrays (bf16): frag[((kc*8+nt)*64+L)*8+j] = W[kc*32+(L>>4)*8+j][nt*16+(L&15)]
// arr0: Wd2  arr1: Wd2^T  arr2: We2  arr3: We3 ; then Wd1zT (fp32 128x64).
__global__ __launch_bounds__(256)
void prep_kernel(const float* __restrict__ Wd2, const float* __restrict__ We2,
                 const float* __restrict__ We3, const float* __restrict__ Wd1,
                 ushort* __restrict__ ws) {
  const int id = blockIdx.x * 256 + threadIdx.x;   // 65536 frag + 8192 Wd1zT
  if (id < 65536) {
    const int arr = id >> 14;
    const int e = id & 16383;
    const int j = e & 7, L = (e >> 3) & 63, nt = (e >> 9) & 7, kc = e >> 12;
    const int kk = kc * 32 + (L >> 4) * 8 + j, nn = nt * 16 + (L & 15);
    float v;
    if      (arr == 0) v = Wd2[kk * HD + nn];
    else if (arr == 1) v = Wd2[nn * HD + kk];    // Wd2^T
    else if (arr == 2) v = We2[kk * HD + nn];
    else               v = We3[kk * HD + nn];
    ws[id] = (ushort)bfb(v);
  } else if (id < 65536 + 8192) {
    const int e = id - 65536;                    // Wd1zT[k*64+j] = Wd1[j*128+k]
    const int k = e >> 6, j = e & 63;
    ((float*)(ws + 65536))[e] = Wd1[j * HD + k];
  }
}

__global__ __launch_bounds__(64, 2)
void metanets_kernel(
    const float* __restrict__ x_ctx, const float* __restrict__ y_ctx,
    const float* __restrict__ mask,  const float* __restrict__ z0,
    const float* __restrict__ noises,
    const float* __restrict__ We1, const float* __restrict__ be1,
    const float* __restrict__ be2, const float* __restrict__ be3,
    const float* __restrict__ Wd1, const float* __restrict__ bd1,
    const float* __restrict__ bd2, const float* __restrict__ Wd3,
    const float* __restrict__ bd3,
    const float* __restrict__ Wf1, const float* __restrict__ bf1,
    const float* __restrict__ Wf2, const float* __restrict__ bf2,
    const float* __restrict__ Wf3, const float* __restrict__ bf3,
    const ushort* __restrict__ wsfrag,
    float* __restrict__ out, int steps, float dt, float dco)
{
  __shared__ unsigned int h1f[4096];   // 16KB: h1 / tau (aliased) A-frag units
  __shared__ float zsh[64];
  __shared__ float zw1[128];
  __shared__ float rsh[128];
  __shared__ float dsum[128];
  unsigned int* const tauf = h1f;
  float* const f1sh = (float*)h1f;          // drift hidden1 (h1f dead by then)
  float* const f2sh = (float*)h1f + 128;    // drift hidden2

  const int lane = threadIdx.x & 63;
  const int b = blockIdx.x;
  const int rr = lane & 15, qq = lane >> 4;

  const bh8* Wd2f  = (const bh8*)(wsfrag);
  const bh8* Wd2Tf = (const bh8*)(wsfrag + 16384);
  const bh8* We2f  = (const bh8*)(wsfrag + 32768);
  const bh8* We3f  = (const bh8*)(wsfrag + 49152);
  const float* Wd1zT = (const float*)(wsfrag + 65536);

  const float x0v = x_ctx[(b*NPT + lane)*2 + 0];
  const float x1v = x_ctx[(b*NPT + lane)*2 + 1];
  const float yv  = y_ctx[b*NPT + lane];
  const float mkv = mask[b*NPT + lane];
  const float inv_msum = 1.0f / fmaxf(wsum64(mkv), 1e-6f);
  const float bd3v = bd3[0];

  zsh[lane] = z0[b*ZD + lane];
  wave_sync();

  // ================= encoder =================
  #pragma unroll 1
  for (int kc = 0; kc < 4; ++kc) {             // enc L1 -> h1f (A-frag layout)
    #pragma unroll
    for (int quad = 0; quad < 4; ++quad) {
      unsigned int pw[4];
      #pragma unroll
      for (int jj = 0; jj < 8; jj += 2) {
        const int k = 32*kc + 8*quad + jj;
        const float sA = be1[k]   + x0v*We1[k]   + x1v*We1[HD+k]   + yv*We1[2*HD+k];
        const float sB = be1[k+1] + x0v*We1[k+1] + x1v*We1[HD+k+1] + yv*We1[2*HD+k+1];
        pw[jj>>1] = packbf(sA*sigf(sA), sB*sigf(sB));
      }
      uint4 v4; v4.x = pw[0]; v4.y = pw[1]; v4.z = pw[2]; v4.w = pw[3];
      ((uint4*)h1f)[(kc*4 + qq)*64 + quad*16 + rr] = v4;
    }
  }
  wave_sync();

  {                                            // enc L2+L3 fused per m-tile
    float racc[8];
    #pragma unroll
    for (int i = 0; i < 8; ++i) racc[i] = 0.f;
    #pragma unroll 1
    for (int mt = 0; mt < 4; ++mt) {
      bh8 af[4];
      #pragma unroll
      for (int kc = 0; kc < 4; ++kc) af[kc] = ((const bh8*)h1f)[(kc*4+mt)*64 + lane];
      wave_sync();   // af in regs before aliased scatter
      float mkq[4];
      #pragma unroll
      for (int g = 0; g < 4; ++g) mkq[g] = __shfl(mkv, mt*16 + qq*4 + g, 64);
      #pragma unroll 1
      for (int half = 0; half < 2; ++half) {
        const int h4 = half*4;
        fx4 acc[4];
        #pragma unroll
        for (int i = 0; i < 4; ++i) {
          const float bv = be2[(h4+i)*16 + rr];
          acc[i] = (fx4){bv, bv, bv, bv};
        }
        #pragma unroll
        for (int i = 0; i < 4; ++i) {
          const int nt = h4 + i;
          acc[i] = __builtin_amdgcn_mfma_f32_16x16x32_bf16(af[0], We2f[(0*8+nt)*64+lane], acc[i], 0,0,0);
          acc[i] = __builtin_amdgcn_mfma_f32_16x16x32_bf16(af[1], We2f[(1*8+nt)*64+lane], acc[i], 0,0,0);
          acc[i] = __builtin_amdgcn_mfma_f32_16x16x32_bf16(af[2], We2f[(2*8+nt)*64+lane], acc[i], 0,0,0);
          acc[i] = __builtin_amdgcn_mfma_f32_16x16x32_bf16(af[3], We2f[(3*8+nt)*64+lane], acc[i], 0,0,0);
        }
        #pragma unroll
        for (int i = 0; i < 4; ++i) {
          const int nt = h4 + i;
          #pragma unroll
          for (int g = 0; g < 4; ++g) {
            const float s2 = acc[i][g];
            const unsigned int tb = bfb(s2 * sigf(s2));
            const unsigned int pb = (unsigned int)__shfl_xor((int)tb, 1, 64);
            if ((rr & 1) == 0) {
              const int unit = ((nt>>1)*4 + mt)*64 + (2*(nt&1) + (rr>>3))*16 + 4*qq + g;
              tauf[unit*4 + ((rr&7)>>1)] = tb | (pb << 16);
            }
          }
        }
      }
      wave_sync();   // scatter visible to tf loads
      bh8 tf[4];
      #pragma unroll
      for (int kc = 0; kc < 4; ++kc) tf[kc] = ((const bh8*)tauf)[(kc*4+mt)*64 + lane];
      #pragma unroll 1
      for (int half = 0; half < 2; ++half) {
        const int h4 = half*4;
        fx4 acc[4];
        #pragma unroll
        for (int i = 0; i < 4; ++i) {
          const float bv = be3[(h4+i)*16 + rr];
          acc[i] = (fx4){bv, bv, bv, bv};
        }
        #pragma unroll
        for (int i = 0; i < 4; ++i) {
          const int nt = h4 + i;
          acc[i] = __builtin_amdgcn_mfma_f32_16x16x32_bf16(tf[0], We3f[(0*8+nt)*64+lane], acc[i], 0,0,0);
          acc[i] = __builtin_amdgcn_mfma_f32_16x16x32_bf16(tf[1], We3f[(1*8+nt)*64+lane], acc[i], 0,0,0);
          acc[i] = __builtin_amdgcn_mfma_f32_16x16x32_bf16(tf[2], We3f[(2*8+nt)*64+lane], acc[i], 0,0,0);
          acc[i] = __builtin_amdgcn_mfma_f32_16x16x32_bf16(tf[3], We3f[(3*8+nt)*64+lane], acc[i], 0,0,0);
        }
        #pragma unroll
        for (int i = 0; i < 4; ++i)
          racc[h4+i] += mkq[0]*acc[i][0] + mkq[1]*acc[i][1]
                      + mkq[2]*acc[i][2] + mkq[3]*acc[i][3];
      }
    }
    #pragma unroll
    for (int nt = 0; nt < 8; ++nt) {
      float v = racc[nt];
      v += __shfl_xor(v, 16, 64);
      v += __shfl_xor(v, 32, 64);
      if (lane < 16) rsh[nt*16 + lane] = v * inv_msum;
    }
  }
  wave_sync();

  // ================= Langevin step loop (no block barriers) =================
  for (int st = 0; st < steps; ++st) {
    const float t = (float)st * dt;

    // A: zW1[k] = bd1[k] + sum_j z[j] Wd1[j,k]  (2 cols/lane)
    {
      float a0 = bd1[lane], a1 = bd1[lane + 64];
      #pragma unroll 4
      for (int j = 0; j < 64; ++j) {
        const float zj = zsh[j];
        a0 = fmaf(zj, Wd1[j*HD + lane],      a0);
        a1 = fmaf(zj, Wd1[j*HD + lane + 64], a1);
      }
      zw1[lane] = a0; zw1[lane + 64] = a1;
    }
    wave_sync();

    // B: dec L1 -> h1f (A-frag layout, all kc slices)
    #pragma unroll 1
    for (int kc = 0; kc < 4; ++kc) {
      #pragma unroll
      for (int quad = 0; quad < 4; ++quad) {
        unsigned int pw[4];
        #pragma unroll
        for (int jj = 0; jj < 8; jj += 2) {
          const int k = 32*kc + 8*quad + jj;
          const float sA = zw1[k]   + x0v*Wd1[64*HD + k]   + x1v*Wd1[65*HD + k];
          const float sB = zw1[k+1] + x0v*Wd1[64*HD + k+1] + x1v*Wd1[65*HD + k+1];
          pw[jj>>1] = packbf(sA*sigf(sA), sB*sigf(sB));
        }
        uint4 v4; v4.x = pw[0]; v4.y = pw[1]; v4.z = pw[2]; v4.w = pw[3];
        ((uint4*)h1f)[(kc*4 + qq)*64 + quad*16 + rr] = v4;
      }
    }
    wave_sync();

    // C: fused fwd+bwd per m-tile
    float dsum8[8];
    #pragma unroll
    for (int i = 0; i < 8; ++i) dsum8[i] = 0.f;
    #pragma unroll 1
    for (int mt = 0; mt < 4; ++mt) {
      bh8 af[4];
      #pragma unroll
      for (int kc = 0; kc < 4; ++kc) af[kc] = ((const bh8*)h1f)[(kc*4+mt)*64 + lane];
      wave_sync();   // af in regs before aliased scatter
      float x0q[4], x1q[4], yq[4], mkq[4];
      #pragma unroll
      for (int g = 0; g < 4; ++g) {
        const int src = mt*16 + qq*4 + g;
        x0q[g] = __shfl(x0v, src, 64);
        x1q[g] = __shfl(x1v, src, 64);
        yq[g]  = __shfl(yv,  src, 64);
        mkq[g] = __shfl(mkv, src, 64);
      }
      float da[4] = {0.f, 0.f, 0.f, 0.f};
      #pragma unroll 1
      for (int half = 0; half < 2; ++half) {
        const int h4 = half*4;
        fx4 acc[4];
        #pragma unroll
        for (int i = 0; i < 4; ++i) {
          const float bv = bd2[(h4+i)*16 + rr];
          acc[i] = (fx4){bv, bv, bv, bv};
        }
        #pragma unroll
        for (int i = 0; i < 4; ++i) {
          const int nt = h4 + i;
          acc[i] = __builtin_amdgcn_mfma_f32_16x16x32_bf16(af[0], Wd2f[(0*8+nt)*64+lane], acc[i], 0,0,0);
          acc[i] = __builtin_amdgcn_mfma_f32_16x16x32_bf16(af[1], Wd2f[(1*8+nt)*64+lane], acc[i], 0,0,0);
          acc[i] = __builtin_amdgcn_mfma_f32_16x16x32_bf16(af[2], Wd2f[(2*8+nt)*64+lane], acc[i], 0,0,0);
          acc[i] = __builtin_amdgcn_mfma_f32_16x16x32_bf16(af[3], Wd2f[(3*8+nt)*64+lane], acc[i], 0,0,0);
        }
        #pragma unroll
        for (int i = 0; i < 4; ++i) {
          const int nt = h4 + i;
          const float w3 = Wd3[nt*16 + rr];
          #pragma unroll
          for (int g = 0; g < 4; ++g) {
            const float s2 = acc[i][g];
            const float sg = sigf(s2);
            da[g] = fmaf(s2*sg, w3, da[g]);
            const unsigned int tb = bfb(w3 * (sg * fmaf(s2, 1.0f - sg, 1.0f)));
            const unsigned int pb = (unsigned int)__shfl_xor((int)tb, 1, 64);
            if ((rr & 1) == 0) {
              const int unit = ((nt>>1)*4 + mt)*64 + (2*(nt&1) + (rr>>3))*16 + 4*qq + g;
              tauf[unit*4 + ((rr&7)>>1)] = tb | (pb << 16);
            }
          }
        }
      }
      float ebw[4];
      #pragma unroll
      for (int g = 0; g < 4; ++g) {
        float v = da[g];
        v += __shfl_xor(v, 1, 64);
        v += __shfl_xor(v, 2, 64);
        v += __shfl_xor(v, 4, 64);
        v += __shfl_xor(v, 8, 64);
        ebw[g] = t * mkq[g] * (v + bd3v - yq[g]);
      }
      wave_sync();   // tau scatter visible
      bh8 tf[4];
      #pragma unroll
      for (int kc = 0; kc < 4; ++kc) tf[kc] = ((const bh8*)tauf)[(kc*4+mt)*64 + lane];
      #pragma unroll 1
      for (int half = 0; half < 2; ++half) {
        const int h4 = half*4;
        fx4 u[4];
        #pragma unroll
        for (int i = 0; i < 4; ++i) u[i] = (fx4){0.f, 0.f, 0.f, 0.f};
        #pragma unroll
        for (int i = 0; i < 4; ++i) {
          const int nt = h4 + i;
          u[i] = __builtin_amdgcn_mfma_f32_16x16x32_bf16(tf[0], Wd2Tf[(0*8+nt)*64+lane], u[i], 0,0,0);
          u[i] = __builtin_amdgcn_mfma_f32_16x16x32_bf16(tf[1], Wd2Tf[(1*8+nt)*64+lane], u[i], 0,0,0);
          u[i] = __builtin_amdgcn_mfma_f32_16x16x32_bf16(tf[2], Wd2Tf[(2*8+nt)*64+lane], u[i], 0,0,0);
          u[i] = __builtin_amdgcn_mfma_f32_16x16x32_bf16(tf[3], Wd2Tf[(3*8+nt)*64+lane], u[i], 0,0,0);
        }
        #pragma unroll
        for (int i = 0; i < 4; ++i) {
          const int nt = h4 + i;
          const int k = nt*16 + rr;
          const float zv = zw1[k];
          const float wa = Wd1[64*HD + k];
          const float wb = Wd1[65*HD + k];
          float snt = 0.f;
          #pragma unroll
          for (int g = 0; g < 4; ++g) {
            const float s1 = zv + x0q[g]*wa + x1q[g]*wb;
            const float sg = sigf(s1);
            snt += ebw[g] * (sg * fmaf(s1, 1.0f - sg, 1.0f)) * u[i][g];
          }
          dsum8[nt] += snt;
        }
      }
    }
    #pragma unroll
    for (int nt = 0; nt < 8; ++nt) {
      float v = dsum8[nt];
      v += __shfl_xor(v, 16, 64);
      v += __shfl_xor(v, 32, 64);
      if (lane < 16) dsum[nt*16 + lane] = v;
    }
    wave_sync();

    // D: drift MLP (2 cols/lane); f1/f2 live in dead h1f space
    {
      float p0 = fmaf(t, Wf1[192*HD + lane],      bf1[lane]);
      float p1 = fmaf(t, Wf1[192*HD + lane + 64], bf1[lane + 64]);
      float q0 = 0.f, q1 = 0.f;
      #pragma unroll 4
      for (int j = 0; j < 64; ++j) {
        const float zj = zsh[j];
        p0 = fmaf(zj, Wf1[j*HD + lane],      p0);
        p1 = fmaf(zj, Wf1[j*HD + lane + 64], p1);
      }
      #pragma unroll 4
      for (int j = 0; j < 128; ++j) {
        const float rj = rsh[j];
        q0 = fmaf(rj, Wf1[(64+j)*HD + lane],      q0);
        q1 = fmaf(rj, Wf1[(64+j)*HD + lane + 64], q1);
      }
      const float a0 = p0 + q0, a1 = p1 + q1;
      f1sh[lane]      = a0 * sigf(a0);
      f1sh[lane + 64] = a1 * sigf(a1);
    }
    wave_sync();
    {
      float p0 = bf2[lane], p1 = bf2[lane + 64];
      #pragma unroll 4
      for (int j = 0; j < 128; ++j) {
        const float fj = f1sh[j];
        p0 = fmaf(fj, Wf2[j*HD + lane],      p0);
        p1 = fmaf(fj, Wf2[j*HD + lane + 64], p1);
      }
      f2sh[lane]      = p0 * sigf(p0);
      f2sh[lane + 64] = p1 * sigf(p1);
    }
    wave_sync();
    {
      float p0 = bf3[lane], gz = 0.f;
      #pragma unroll 4
      for (int h = 0; h < 128; ++h) {
        p0 = fmaf(f2sh[h], Wf3[h*ZD + lane],   p0);
        gz = fmaf(dsum[h], Wd1zT[h*ZD + lane], gz);
      }
      const float zold = zsh[lane];
      float g = zold + gz;                    // t already folded into ebw
      g = fminf(fmaxf(g, -100.0f), 100.0f);
      const float zn = zold + (p0 - g) * dt
                     + dco * noises[(size_t)st * (B_TOT * ZD) + b * ZD + lane];
      wave_sync();
      zsh[lane] = zn;
      wave_sync();
    }
  }

  out[b*ZD + lane] = zsh[lane];
}

extern "C" void kernel_launch(void* const* d_in, const int* in_sizes, int n_in,
                              void* d_out, int out_size, void* d_ws, size_t ws_size,
                              hipStream_t stream) {
  const float* x_ctx  = (const float*)d_in[0];
  const float* y_ctx  = (const float*)d_in[1];
  const float* mask   = (const float*)d_in[2];
  const float* z0     = (const float*)d_in[3];
  const float* noises = (const float*)d_in[4];
  const float* We1 = (const float*)d_in[5];  const float* be1 = (const float*)d_in[6];
  const float* We2 = (const float*)d_in[7];  const float* be2 = (const float*)d_in[8];
  const float* We3 = (const float*)d_in[9];  const float* be3 = (const float*)d_in[10];
  const float* Wd1 = (const float*)d_in[11]; const float* bd1 = (const float*)d_in[12];
  const float* Wd2 = (const float*)d_in[13]; const float* bd2 = (const float*)d_in[14];
  const float* Wd3 = (const float*)d_in[15]; const float* bd3 = (const float*)d_in[16];
  const float* Wf1 = (const float*)d_in[17]; const float* bf1 = (const float*)d_in[18];
  const float* Wf2 = (const float*)d_in[19]; const float* bf2 = (const float*)d_in[20];
  const float* Wf3 = (const float*)d_in[21]; const float* bf3 = (const float*)d_in[22];

  const int steps = in_sizes[4] / (B_TOT * ZD);
  const float dt  = 1.0f / (float)steps;
  const float dco = (float)sqrt(2.0 / (double)steps);

  ushort* wsu = (ushort*)d_ws;   // 128KB frags + 32KB Wd1zT

  hipLaunchKernelGGL(prep_kernel, dim3(288), dim3(256), 0, stream,
                     Wd2, We2, We3, Wd1, wsu);
  hipLaunchKernelGGL(metanets_kernel, dim3(B_TOT), dim3(64), 0, stream,
      x_ctx, y_ctx, mask, z0, noises,
      We1, be1, be2, be3,
      Wd1, bd1, bd2, Wd3, bd3,
      Wf1, bf1, Wf2, bf2, Wf3, bf3,
      wsu, (float*)d_out, steps, dt, dco);
}